// Round 4
// baseline (517.831 us; speedup 1.0000x reference)
//
#include <hip/hip_runtime.h>
#include <stdint.h>

// Problem: B=32, C=256 (in=out), P=2 pods, spatial 64x64 (pos=4096).
// R3: I/O is FLOAT32 (reference-faithful; bf16 misread of f32 explains the
// persistent NaN: low u16 of a float has a random bf16 exponent -> Inf/NaN).
// Internals bf16 (MFMA GEMM). ZERO d_ws use: d_out (128 MiB) is 8192 slots of
// 16 KiB (one per image i = b*256 + ch):
//   slot lower 8 KiB: f1t (K1a->K1b), later f6 (K2->K3)  [temporally disjoint]
//   slot upper 8 KiB: F[b][pos][c] bf16 via linear->slot address map Faddr()
// K3 is per-slot in-place: reads own lower half, writes own full slot as f32.
//
// Pipeline:
//   K1a: per img: WHT along w, write f1t[w][h] bf16 (transposed) -> slot lo
//   K1b: per (b,cg32,wg8): WHT along h, write F[b][pos][c] bf16 -> slot hi
//   K2 : Z = Wcat(512x256,rows m=2o+p from W f32) @ F[b]; epilogue v-scale,
//        soft-threshold both pods, + residual f2 -> f6[b][o][pos] -> slot lo
//   K3 : per img: inverse 2D WHT /4096 -> f32 full slot (residual already in)

typedef __attribute__((ext_vector_type(4))) float f32x4_t;
typedef __attribute__((ext_vector_type(8))) __bf16 bf16x8_t;
typedef __attribute__((ext_vector_type(8))) unsigned short u16x8_t;

__device__ __forceinline__ float bf2f(unsigned short u) {
  union { unsigned int i; float f; } x; x.i = ((unsigned int)u) << 16; return x.f;
}
__device__ __forceinline__ unsigned short f2bf(float f) {
  union { float f; unsigned int i; } x; x.f = f;
  unsigned int i = x.i;
  return (unsigned short)((i + 0x7FFFu + ((i >> 16) & 1u)) >> 16);
}
// linear u16 index into F -> physical u16 offset in d_out (slot upper halves)
__device__ __forceinline__ size_t Faddr(size_t f) {
  return ((f >> 12) << 13) + 4096 + (f & 4095);
}

// ---------------- K1a: WHT along w, write transposed [w][h] bf16 ----------------
__global__ __launch_bounds__(256) void k_wht_w(const float* __restrict__ x,
                                               unsigned short* __restrict__ obuf) {
  __shared__ float tile[64 * 65];
  int tid = threadIdx.x;
  size_t ibase = (size_t)blockIdx.x * 4096;      // x f32 index (img = b*256+c)
  size_t obase = (size_t)blockIdx.x * 8192;      // d_out slot base (u16 units)

#pragma unroll
  for (int i = 0; i < 4; i++) {
    int q = i * 256 + tid;                       // float4 chunk
    int e = q * 4;
    int row = e >> 6, col = e & 63;
    f32x4_t sv = *(const f32x4_t*)(x + ibase + e);
#pragma unroll
    for (int j = 0; j < 4; j++) tile[row * 65 + col + j] = sv[j];
  }
  __syncthreads();

#pragma unroll
  for (int s = 1; s < 64; s <<= 1) {             // butterflies along w (cols)
#pragma unroll
    for (int i = 0; i < 8; i++) {
      int idx = i * 256 + tid;                   // 2048 pairs
      int row = idx >> 5, j = idx & 31;
      int w0 = ((j & ~(s - 1)) << 1) | (j & (s - 1));
      float a = tile[row * 65 + w0];
      float b = tile[row * 65 + w0 + s];
      tile[row * 65 + w0] = a + b;
      tile[row * 65 + w0 + s] = a - b;
    }
    __syncthreads();
  }

  // write transposed: f1t[w*64 + h] bf16, slot lower half
#pragma unroll
  for (int i = 0; i < 8; i++) {
    int idx = i * 256 + tid;                     // u32 (2 bf16); idx < 2048
    int e = idx * 2;
    int w = e >> 6, h = e & 63;
    unsigned int pk = (unsigned int)f2bf(tile[h * 65 + w]) |
                      ((unsigned int)f2bf(tile[(h + 1) * 65 + w]) << 16);
    *(unsigned int*)(obuf + obase + e) = pk;
  }
}

// ---------------- K1b: WHT along h, write F[b][pos][c] bf16 ----------------
__global__ __launch_bounds__(256) void k_wht_h(unsigned short* __restrict__ obuf) {
  __shared__ float t2[512 * 32];                 // [w*64+h][c], 64 KiB
  int tid = threadIdx.x;
  int c0 = blockIdx.x * 32;                      // 8 c-groups
  int j0 = blockIdx.y * 8;                       // 8 w-groups
  int b  = blockIdx.z;

  // load: 32c x 8w x 64h bf16 from slot lower halves, contiguous along h
#pragma unroll
  for (int i = 0; i < 8; i++) {
    int q = i * 256 + tid;                       // 2048 chunks of 8
    int hq = q & 7, j = (q >> 3) & 7, c = q >> 6;
    size_t g = (size_t)(b * 256 + c0 + c) * 8192 + (j0 + j) * 64 + hq * 8;
    u16x8_t sv = *(const u16x8_t*)(obuf + g);
    int hb = hq * 8;
#pragma unroll
    for (int jj = 0; jj < 8; jj++) t2[(j * 64 + hb + jj) * 32 + c] = bf2f(sv[jj]);
  }
  __syncthreads();

  // butterflies along h (stride 32 in t2)
#pragma unroll
  for (int s = 1; s < 64; s <<= 1) {
#pragma unroll
    for (int i = 0; i < 32; i++) {
      int idx = i * 256 + tid;                   // 8192 pairs
      int c = idx & 31;
      int rest = idx >> 5;
      int pj = rest & 31, j = rest >> 5;
      int h0 = ((pj & ~(s - 1)) << 1) | (pj & (s - 1));
      int a0 = (j * 64 + h0) * 32 + c;
      int a1 = a0 + s * 32;
      float a = t2[a0], bb = t2[a1];
      t2[a0] = a + bb;
      t2[a1] = a - bb;
    }
    __syncthreads();
  }

  // write F[b][pos = k*64 + (j0+jj)][c], 2 c per u32, via Faddr
#pragma unroll
  for (int i = 0; i < 32; i++) {
    int idx = i * 256 + tid;                     // 8192 u32
    int c2 = (idx & 15) * 2;
    int posidx = idx >> 4;                       // 0..511
    int k = posidx >> 3, jj = posidx & 7;
    int pos = k * 64 + j0 + jj;
    size_t f = ((size_t)b * 4096 + pos) * 256 + c0 + c2;
    unsigned int pk = (unsigned int)f2bf(t2[(jj * 64 + k) * 32 + c2]) |
                      ((unsigned int)f2bf(t2[(jj * 64 + k) * 32 + c2 + 1]) << 16);
    *(unsigned int*)(obuf + Faddr(f)) = pk;
  }
}

// ---------------- K2: GEMM + soft-threshold epilogue ----------------
// A rows m = 2o+p map to W[p][o][c] (f32) by address math; cvt to bf16 on stage.
__global__ __launch_bounds__(256) void k_gemm(const float* __restrict__ Wf,
                                              const float* __restrict__ vv,
                                              const float* __restrict__ TT,
                                              unsigned short* __restrict__ obuf) {
  __shared__ unsigned short Alds[128 * 64];      // [r][k] 8x16B chunks, xor-swizzled
  __shared__ unsigned short Blds[128 * 64];
  int tid = threadIdx.x;
  int lane = tid & 63, wave = tid >> 6;
  int quad = lane >> 4, l15 = lane & 15;
  int wm = wave & 1, wn = wave >> 1;
  int n0 = blockIdx.x * 128;                     // pos tile (32)
  int m0 = blockIdx.y * 128;                     // Wcat row tile (4)
  int b  = blockIdx.z;
  size_t fB0 = (size_t)b * 4096 * 256;           // F linear base for this batch

  f32x4_t acc[4][4];
#pragma unroll
  for (int mt = 0; mt < 4; mt++)
#pragma unroll
    for (int nt = 0; nt < 4; nt++)
      acc[mt][nt] = (f32x4_t){0.f, 0.f, 0.f, 0.f};

  for (int ks = 0; ks < 4; ++ks) {
    int k0 = ks * 64;
    u16x8_t va[4], vb[4];
#pragma unroll
    for (int i = 0; i < 4; i++) {
      int idx = i * 256 + tid;                   // 1024 chunks of 8 elems
      int r = idx >> 3, cch = idx & 7;
      int gch = cch ^ (r & 7);
      int m = m0 + r;                            // row m = 2o+p
      const float* wp = Wf + ((m & 1) << 16) + ((m >> 1) << 8) + k0 + gch * 8;
      f32x4_t w0 = *(const f32x4_t*)wp;
      f32x4_t w1 = *(const f32x4_t*)(wp + 4);
#pragma unroll
      for (int j = 0; j < 4; j++) { va[i][j] = f2bf(w0[j]); va[i][4 + j] = f2bf(w1[j]); }
      vb[i] = *(const u16x8_t*)(obuf + Faddr(fB0 + (size_t)(n0 + r) * 256 + k0 + gch * 8));
    }
#pragma unroll
    for (int i = 0; i < 4; i++) {
      int idx = i * 256 + tid;
      *(u16x8_t*)&Alds[idx * 8] = va[i];
      *(u16x8_t*)&Blds[idx * 8] = vb[i];
    }
    __syncthreads();

#pragma unroll
    for (int kk = 0; kk < 2; ++kk) {
      bf16x8_t af[4], bfr[4];
#pragma unroll
      for (int mt = 0; mt < 4; mt++) {
        int row = wm * 64 + mt * 16 + l15;
        int ch = (kk * 4 + quad) ^ (row & 7);
        af[mt] = *(const bf16x8_t*)&Alds[row * 64 + ch * 8];
      }
#pragma unroll
      for (int nt = 0; nt < 4; nt++) {
        int row = wn * 64 + nt * 16 + l15;
        int ch = (kk * 4 + quad) ^ (row & 7);
        bfr[nt] = *(const bf16x8_t*)&Blds[row * 64 + ch * 8];
      }
#pragma unroll
      for (int mt = 0; mt < 4; mt++)
#pragma unroll
        for (int nt = 0; nt < 4; nt++)
          acc[mt][nt] = __builtin_amdgcn_mfma_f32_16x16x32_bf16(af[mt], bfr[nt], acc[mt][nt], 0, 0, 0);
    }
    __syncthreads();
  }

  // epilogue: rows m=2o+p interleaved -> pods in adjacent acc regs
  // C/D layout: col(n)=lane&15, row(m within 16)=quad*4+reg
#pragma unroll
  for (int nt = 0; nt < 4; nt++) {
    int pos = n0 + wn * 64 + nt * 16 + l15;
    float v0 = vv[pos],  v1 = vv[4096 + pos];
    float t0 = TT[pos],  t1 = TT[4096 + pos];
#pragma unroll
    for (int mt = 0; mt < 4; mt++) {
      int obase = (m0 >> 1) + wm * 32 + mt * 8 + quad * 2;
#pragma unroll
      for (int rp = 0; rp < 2; rp++) {
        int o = obase + rp;
        float z0 = acc[mt][nt][rp * 2 + 0] * v0;
        float z1 = acc[mt][nt][rp * 2 + 1] * v1;
        float s0 = copysignf(fmaxf(fabsf(z0) - t0, 0.f), z0);
        float s1 = copysignf(fmaxf(fabsf(z1) - t1, 0.f), z1);
        // residual f2[b][c=o][pos] read from F
        float res = bf2f(obuf[Faddr(fB0 + (size_t)pos * 256 + o)]);
        // f6 -> slot lower half of img (b,o)
        obuf[(size_t)(b * 256 + o) * 8192 + pos] = f2bf(s0 + s1 + res);
      }
    }
  }
}

// ---------------- K3: inverse 2D WHT /4096, per-slot in-place ----------------
__global__ __launch_bounds__(256) void k_iwht(unsigned short* __restrict__ obuf) {
  __shared__ float tile[64 * 65];
  int tid = threadIdx.x;
  size_t ub = (size_t)blockIdx.x * 8192;         // f6 base (u16), slot lower half
  size_t fb = (size_t)blockIdx.x * 4096;         // out base (f32) = same slot
  float* outf = (float*)obuf;

#pragma unroll
  for (int i = 0; i < 2; i++) {
    int q = i * 256 + tid;
    int e = q * 8;
    int row = e >> 6, col = e & 63;
    u16x8_t sv = *(const u16x8_t*)(obuf + ub + e);
#pragma unroll
    for (int j = 0; j < 8; j++) tile[row * 65 + col + j] = bf2f(sv[j]);
  }
  __syncthreads();

#pragma unroll
  for (int s = 1; s < 64; s <<= 1) {             // along w
#pragma unroll
    for (int i = 0; i < 8; i++) {
      int idx = i * 256 + tid;
      int row = idx >> 5, j = idx & 31;
      int w0 = ((j & ~(s - 1)) << 1) | (j & (s - 1));
      float a = tile[row * 65 + w0], bb = tile[row * 65 + w0 + s];
      tile[row * 65 + w0] = a + bb;
      tile[row * 65 + w0 + s] = a - bb;
    }
    __syncthreads();
  }
#pragma unroll
  for (int s = 1; s < 64; s <<= 1) {             // along h
#pragma unroll
    for (int i = 0; i < 8; i++) {
      int idx = i * 256 + tid;
      int col = idx & 63, hp = idx >> 6;
      int h0 = ((hp & ~(s - 1)) << 1) | (hp & (s - 1));
      float a = tile[h0 * 65 + col], bb = tile[(h0 + s) * 65 + col];
      tile[h0 * 65 + col] = a + bb;
      tile[(h0 + s) * 65 + col] = a - bb;
    }
    __syncthreads();
  }

  const float sc = 1.0f / 4096.0f;
#pragma unroll
  for (int i = 0; i < 4; i++) {
    int q = i * 256 + tid;
    int e = q * 4;
    int row = e >> 6, col = e & 63;
    f32x4_t ov;
#pragma unroll
    for (int j = 0; j < 4; j++) ov[j] = tile[row * 65 + col + j] * sc;
    *(f32x4_t*)(outf + fb + e) = ov;
  }
}

extern "C" void kernel_launch(void* const* d_in, const int* in_sizes, int n_in,
                              void* d_out, int out_size, void* d_ws, size_t ws_size,
                              hipStream_t stream) {
  const float* x = (const float*)d_in[0];        // (32,256,64,64) f32
  const float* v = (const float*)d_in[1];        // (2,64,64) f32
  const float* W = (const float*)d_in[2];        // (2,256,256) f32
  const float* T = (const float*)d_in[3];        // (2,64,64) f32
  unsigned short* obuf = (unsigned short*)d_out; // 128 MiB scratch slots -> f32 out
  (void)d_ws; (void)ws_size; (void)in_sizes; (void)n_in; (void)out_size;

  k_wht_w<<<8192, 256, 0, stream>>>(x, obuf);
  k_wht_h<<<dim3(8, 8, 32), 256, 0, stream>>>(obuf);
  k_gemm<<<dim3(32, 4, 32), 256, 0, stream>>>(W, v, T, obuf);
  k_iwht<<<8192, 256, 0, stream>>>(obuf);
}

// Round 5
// 342.316 us; speedup vs baseline: 1.5127x; 1.5127x over previous
//
#include <hip/hip_runtime.h>
#include <stdint.h>

// B=32, C=256, P=2 pods, 64x64 spatial (pos=4096). f32 I/O, bf16 MFMA inside.
// R4: WHT kernels rewritten as MFMA GEMMs with H (+-1) generated in registers.
//   k_fwd: per wave (1 image): T1 = X*H (MFMA), LDS transpose, f2 = H*T1 (MFMA),
//          cross-wave LDS repack -> F[b][c/8][pos][c%8] bf16 (coalesced 16B).
//   k_gemm: Z = Wcat(512x256, rows m=2o+p) @ F; epilogue v-scale + soft-thr
//          (NO residual), LDS repack -> f6[b][o][pos] coalesced 256B rows.
//   k_inv: per wave (1 image): V = H*(f6*H) (MFMA), out = V/4096 + x (residual
//          moved here; x reads coalesced). In-place per-slot in d_out.
// d_out slot map (16 KiB per img): lo 8 KiB = f6, hi 8 KiB = F via Faddr().
// d_ws unused.

typedef __attribute__((ext_vector_type(4))) float f32x4_t;
typedef __attribute__((ext_vector_type(8))) __bf16 bf16x8_t;
typedef __attribute__((ext_vector_type(8))) unsigned short u16x8_t;
typedef __attribute__((ext_vector_type(4))) unsigned short u16x4_t;

__device__ __forceinline__ float bf2f(unsigned short u) {
  union { unsigned int i; float f; } x; x.i = ((unsigned int)u) << 16; return x.f;
}
__device__ __forceinline__ unsigned short f2bf(float f) {   // RNE
  union { float f; unsigned int i; } x; x.f = f;
  unsigned int i = x.i;
  return (unsigned short)((i + 0x7FFFu + ((i >> 16) & 1u)) >> 16);
}
__device__ __forceinline__ unsigned short f2bf_t(float f) { // truncate (staging)
  union { float f; unsigned int i; } x; x.f = f;
  return (unsigned short)(x.i >> 16);
}
// linear u16 index into F -> physical u16 offset in d_out (slot upper halves)
__device__ __forceinline__ size_t Faddr(size_t f) {
  return ((f >> 12) << 13) + 4096 + (f & 4095);
}

// ---------------- k_fwd: 2D WHT via MFMA, write F tiled ----------------
// block = 512 thr = 8 waves, wave -> image c = cg*8+wave; grid (32 cg, 32 b)
__global__ __launch_bounds__(512) void k_fwd(const float* __restrict__ x,
                                             unsigned short* __restrict__ obuf) {
  __shared__ unsigned short smem[36864];       // 72 KiB: 8x T1t(4608) / Fbuf overlay
  int tid = threadIdx.x;
  int lane = tid & 63, wave = tid >> 6;
  int quad = lane >> 4, l15 = lane & 15;
  int cg = blockIdx.x, b = blockIdx.y;
  size_t img = (size_t)b * 256 + cg * 8 + wave;
  unsigned short* T1t = smem + wave * 4608;    // [64 rows][72 u16] (9216 B, 16B-mult)

  // H fragments: hf[kc][t][j] = sign(parity((kc*32+quad*8+j) & (t*16+l15)))
  // symmetric formula serves as B-frag (n=t) for GEMM1 and A-frag (m=t) for GEMM2
  bf16x8_t hf[2][4];
#pragma unroll
  for (int kc = 0; kc < 2; kc++)
#pragma unroll
    for (int t = 0; t < 4; t++) {
      bf16x8_t h;
#pragma unroll
      for (int j = 0; j < 8; j++) {
        int k = kc * 32 + quad * 8 + j, n = t * 16 + l15;
        h[j] = (__builtin_popcount(k & n) & 1) ? (__bf16)-1.0f : (__bf16)1.0f;
      }
      hf[kc][t] = h;
    }

  // X A-fragments (f32 -> bf16 trunc)
  bf16x8_t xa[4][2];
#pragma unroll
  for (int mt = 0; mt < 4; mt++)
#pragma unroll
    for (int kc = 0; kc < 2; kc++) {
      const float* p = x + img * 4096 + (mt * 16 + l15) * 64 + kc * 32 + quad * 8;
      f32x4_t a0 = *(const f32x4_t*)p;
      f32x4_t a1 = *(const f32x4_t*)(p + 4);
      u16x8_t u;
#pragma unroll
      for (int j = 0; j < 4; j++) { u[j] = f2bf_t(a0[j]); u[4 + j] = f2bf_t(a1[j]); }
      xa[mt][kc] = *(bf16x8_t*)&u;
    }

  // GEMM1: T1 = X*H, strip-mined by nt; store transposed [kw][h] into T1t
#pragma unroll
  for (int nt = 0; nt < 4; nt++) {
    f32x4_t a1c[4];
#pragma unroll
    for (int mt = 0; mt < 4; mt++) a1c[mt] = (f32x4_t){0.f, 0.f, 0.f, 0.f};
#pragma unroll
    for (int kc = 0; kc < 2; kc++)
#pragma unroll
      for (int mt = 0; mt < 4; mt++)
        a1c[mt] = __builtin_amdgcn_mfma_f32_16x16x32_bf16(xa[mt][kc], hf[kc][nt], a1c[mt], 0, 0, 0);
#pragma unroll
    for (int mt = 0; mt < 4; mt++) {
      u16x4_t t4;
#pragma unroll
      for (int r = 0; r < 4; r++) t4[r] = f2bf_t(a1c[mt][r]);
      *(u16x4_t*)&T1t[(nt * 16 + l15) * 72 + mt * 16 + quad * 4] = t4;  // 8B aligned
    }
  }

  // GEMM2: f2 = H*T1 (A=H gen, B from T1t b128 reads)
  f32x4_t acc[4][4];
#pragma unroll
  for (int mt = 0; mt < 4; mt++)
#pragma unroll
    for (int nt = 0; nt < 4; nt++) acc[mt][nt] = (f32x4_t){0.f, 0.f, 0.f, 0.f};
#pragma unroll
  for (int kc = 0; kc < 2; kc++)
#pragma unroll
    for (int nt = 0; nt < 4; nt++) {
      bf16x8_t bfr = *(bf16x8_t*)&T1t[(nt * 16 + l15) * 72 + kc * 32 + quad * 8];
#pragma unroll
      for (int mt = 0; mt < 4; mt++)
        acc[mt][nt] = __builtin_amdgcn_mfma_f32_16x16x32_bf16(hf[kc][mt], bfr, acc[mt][nt], 0, 0, 0);
    }

  __syncthreads();                             // all T1t reads done before overlay
  // fill Fbuf[pos][c8]: this wave supplies c-lane = wave
#pragma unroll
  for (int mt = 0; mt < 4; mt++)
#pragma unroll
    for (int nt = 0; nt < 4; nt++)
#pragma unroll
      for (int r = 0; r < 4; r++) {
        int pos = (mt * 16 + quad * 4 + r) * 64 + nt * 16 + l15;  // kh*64+kw
        smem[pos * 8 + wave] = f2bf(acc[mt][nt][r]);
      }
  __syncthreads();
  // drain: coalesced u16x8 stores to F via Faddr
  size_t fbase = ((size_t)b * 32 + cg) * 4096;
#pragma unroll
  for (int i = 0; i < 8; i++) {
    int pos = i * 512 + tid;
    u16x8_t vch = *(u16x8_t*)&smem[pos * 8];
    *(u16x8_t*)(obuf + Faddr((fbase + pos) * 8)) = vch;
  }
}

// ---------------- k_gemm: Wcat @ F + soft-threshold ----------------
__global__ __launch_bounds__(256) void k_gemm(const float* __restrict__ Wf,
                                              const float* __restrict__ vv,
                                              const float* __restrict__ TT,
                                              unsigned short* __restrict__ obuf) {
  __shared__ unsigned short smem2[16384];      // A(8192) + B(8192); epi overlay
  unsigned short* Alds = smem2;
  unsigned short* Blds = smem2 + 8192;
  int tid = threadIdx.x;
  int lane = tid & 63, wave = tid >> 6;
  int quad = lane >> 4, l15 = lane & 15;
  int wm = wave & 1, wn = wave >> 1;
  int n0 = blockIdx.x * 128;                   // pos tile
  int m0 = blockIdx.y * 128;                   // Wcat row tile (m=2o+p)
  int b  = blockIdx.z;

  f32x4_t acc[4][4];
#pragma unroll
  for (int mt = 0; mt < 4; mt++)
#pragma unroll
    for (int nt = 0; nt < 4; nt++) acc[mt][nt] = (f32x4_t){0.f, 0.f, 0.f, 0.f};

  for (int ks = 0; ks < 4; ++ks) {
    int k0 = ks * 64;
    u16x8_t va[4], vb[4];
#pragma unroll
    for (int i = 0; i < 4; i++) {
      int idx = i * 256 + tid;
      {                                        // A: W f32 -> bf16, chunk-swizzled fetch
        int r = idx >> 3, cch = idx & 7;
        int gch = cch ^ (r & 7);
        int m = m0 + r;
        const float* wp = Wf + ((m & 1) << 16) + ((m >> 1) << 8) + k0 + gch * 8;
        f32x4_t w0 = *(const f32x4_t*)wp;
        f32x4_t w1 = *(const f32x4_t*)(wp + 4);
        u16x8_t u;
#pragma unroll
        for (int j = 0; j < 4; j++) { u[j] = f2bf_t(w0[j]); u[4 + j] = f2bf_t(w1[j]); }
        va[i] = u;
      }
      {                                        // B: coalesced fetch, swizzled LDS slot
        int r = idx & 127, cch = idx >> 7;
        size_t f = (((size_t)b * 32 + ks * 8 + cch) * 4096 + n0 + r) * 8;
        vb[i] = *(const u16x8_t*)(obuf + Faddr(f));
      }
    }
#pragma unroll
    for (int i = 0; i < 4; i++) {
      int idx = i * 256 + tid;
      *(u16x8_t*)&Alds[idx * 8] = va[i];       // A: slot cch holds global gch
      int r = idx & 127, cch = idx >> 7;
      int s = cch ^ (r & 7);
      *(u16x8_t*)&Blds[r * 64 + s * 8] = vb[i];// B: slot s holds global cch
    }
    __syncthreads();

#pragma unroll
    for (int kk = 0; kk < 2; ++kk) {
      bf16x8_t af[4], bfr[4];
#pragma unroll
      for (int mt = 0; mt < 4; mt++) {
        int row = wm * 64 + mt * 16 + l15;
        int ch = (kk * 4 + quad) ^ (row & 7);
        af[mt] = *(const bf16x8_t*)&Alds[row * 64 + ch * 8];
      }
#pragma unroll
      for (int nt = 0; nt < 4; nt++) {
        int row = wn * 64 + nt * 16 + l15;
        int ch = (kk * 4 + quad) ^ (row & 7);
        bfr[nt] = *(const bf16x8_t*)&Blds[row * 64 + ch * 8];
      }
#pragma unroll
      for (int mt = 0; mt < 4; mt++)
#pragma unroll
        for (int nt = 0; nt < 4; nt++)
          acc[mt][nt] = __builtin_amdgcn_mfma_f32_16x16x32_bf16(af[mt], bfr[nt], acc[mt][nt], 0, 0, 0);
    }
    __syncthreads();
  }

  // epilogue: v-scale + soft-threshold both pods (reg parity = pod), NO residual
  // -> LDS tile [64 o][136 pos-stride] -> coalesced f6 row stores
#pragma unroll
  for (int nt = 0; nt < 4; nt++) {
    int posl = wn * 64 + nt * 16 + l15;
    int pos = n0 + posl;
    float v0 = vv[pos], v1 = vv[4096 + pos];
    float t0 = TT[pos], t1 = TT[4096 + pos];
#pragma unroll
    for (int mt = 0; mt < 4; mt++)
#pragma unroll
      for (int rp = 0; rp < 2; rp++) {
        int ol = wm * 32 + mt * 8 + quad * 2 + rp;
        float z0 = acc[mt][nt][rp * 2 + 0] * v0;
        float z1 = acc[mt][nt][rp * 2 + 1] * v1;
        float s0 = copysignf(fmaxf(fabsf(z0) - t0, 0.f), z0);
        float s1 = copysignf(fmaxf(fabsf(z1) - t1, 0.f), z1);
        smem2[ol * 136 + posl] = f2bf(s0 + s1);
      }
  }
  __syncthreads();
  int o0 = m0 >> 1;
#pragma unroll
  for (int i = 0; i < 4; i++) {
    int ci = i * 256 + tid;                    // 1024 chunks = 64 rows x 16
    int row = ci >> 4, cc = ci & 15;
    u16x8_t vch = *(u16x8_t*)&smem2[row * 136 + cc * 8];
    size_t img = (size_t)b * 256 + o0 + row;
    *(u16x8_t*)(obuf + img * 8192 + n0 + cc * 8) = vch;   // slot-lo, coalesced
  }
}

// ---------------- k_inv: inverse 2D WHT via MFMA + /4096 + x ----------------
// block = 256 thr = 4 waves, wave -> image; grid 2048
__global__ __launch_bounds__(256) void k_inv(const float* __restrict__ x,
                                             unsigned short* __restrict__ obuf) {
  __shared__ unsigned short smem[18432];       // 4x T1t(4608)
  int tid = threadIdx.x;
  int lane = tid & 63, wave = tid >> 6;
  int quad = lane >> 4, l15 = lane & 15;
  size_t img = (size_t)blockIdx.x * 4 + wave;
  unsigned short* T1t = smem + wave * 4608;

  bf16x8_t hf[2][4];
#pragma unroll
  for (int kc = 0; kc < 2; kc++)
#pragma unroll
    for (int t = 0; t < 4; t++) {
      bf16x8_t h;
#pragma unroll
      for (int j = 0; j < 8; j++) {
        int k = kc * 32 + quad * 8 + j, n = t * 16 + l15;
        h[j] = (__builtin_popcount(k & n) & 1) ? (__bf16)-1.0f : (__bf16)1.0f;
      }
      hf[kc][t] = h;
    }

  // A-frags from f6 (slot-lo), bf16 16B loads
  bf16x8_t fa[4][2];
#pragma unroll
  for (int mt = 0; mt < 4; mt++)
#pragma unroll
    for (int kc = 0; kc < 2; kc++)
      fa[mt][kc] = *(const bf16x8_t*)(obuf + img * 8192 + (mt * 16 + l15) * 64 + kc * 32 + quad * 8);

  // GEMM1: U = f6*H, strip-mined; store transposed into T1t
#pragma unroll
  for (int nt = 0; nt < 4; nt++) {
    f32x4_t a1c[4];
#pragma unroll
    for (int mt = 0; mt < 4; mt++) a1c[mt] = (f32x4_t){0.f, 0.f, 0.f, 0.f};
#pragma unroll
    for (int kc = 0; kc < 2; kc++)
#pragma unroll
      for (int mt = 0; mt < 4; mt++)
        a1c[mt] = __builtin_amdgcn_mfma_f32_16x16x32_bf16(fa[mt][kc], hf[kc][nt], a1c[mt], 0, 0, 0);
#pragma unroll
    for (int mt = 0; mt < 4; mt++) {
      u16x4_t t4;
#pragma unroll
      for (int r = 0; r < 4; r++) t4[r] = f2bf_t(a1c[mt][r]);
      *(u16x4_t*)&T1t[(nt * 16 + l15) * 72 + mt * 16 + quad * 4] = t4;
    }
  }

  // GEMM2: V = H*U
  f32x4_t acc[4][4];
#pragma unroll
  for (int mt = 0; mt < 4; mt++)
#pragma unroll
    for (int nt = 0; nt < 4; nt++) acc[mt][nt] = (f32x4_t){0.f, 0.f, 0.f, 0.f};
#pragma unroll
  for (int kc = 0; kc < 2; kc++)
#pragma unroll
    for (int nt = 0; nt < 4; nt++) {
      bf16x8_t bfr = *(bf16x8_t*)&T1t[(nt * 16 + l15) * 72 + kc * 32 + quad * 8];
#pragma unroll
      for (int mt = 0; mt < 4; mt++)
        acc[mt][nt] = __builtin_amdgcn_mfma_f32_16x16x32_bf16(hf[kc][mt], bfr, acc[mt][nt], 0, 0, 0);
    }

  // epilogue: out = V/4096 + x (residual), f32, in-place per slot
  float* outf = (float*)obuf;
  const float sc = 1.0f / 4096.0f;
#pragma unroll
  for (int mt = 0; mt < 4; mt++)
#pragma unroll
    for (int nt = 0; nt < 4; nt++)
#pragma unroll
      for (int r = 0; r < 4; r++) {
        int hh = mt * 16 + quad * 4 + r, ww = nt * 16 + l15;
        size_t off = img * 4096 + hh * 64 + ww;
        outf[off] = acc[mt][nt][r] * sc + x[off];
      }
}

extern "C" void kernel_launch(void* const* d_in, const int* in_sizes, int n_in,
                              void* d_out, int out_size, void* d_ws, size_t ws_size,
                              hipStream_t stream) {
  const float* x = (const float*)d_in[0];      // (32,256,64,64) f32
  const float* v = (const float*)d_in[1];      // (2,64,64) f32
  const float* W = (const float*)d_in[2];      // (2,256,256) f32
  const float* T = (const float*)d_in[3];      // (2,64,64) f32
  unsigned short* obuf = (unsigned short*)d_out;
  (void)d_ws; (void)ws_size; (void)in_sizes; (void)n_in; (void)out_size;

  k_fwd<<<dim3(32, 32), 512, 0, stream>>>(x, obuf);
  k_gemm<<<dim3(32, 4, 32), 256, 0, stream>>>(W, v, T, obuf);
  k_inv<<<2048, 256, 0, stream>>>(x, obuf);
}

// Round 6
// 337.496 us; speedup vs baseline: 1.5343x; 1.0143x over previous
//
#include <hip/hip_runtime.h>
#include <stdint.h>

// B=32, C=256, P=2 pods, 64x64 spatial (pos=4096). f32 I/O, bf16 MFMA inside.
// R5: all global streams in k_fwd/k_inv go through LDS repacks (coalesced
// float4/u16x8 global side, fragment-shaped LDS side). k_gemm unchanged (R4).
//   k_fwd: stage x coalesced->LDS bf16 tile; T1=X*H, LDS transpose, f2=H*T1;
//          cross-wave repack -> F[b][c/8][pos][c%8] bf16 (coalesced 16B).
//   k_gemm: Z = Wcat(512x256, rows m=2o+p) @ F; epilogue v-scale + soft-thr,
//          LDS repack -> f6[b][o][pos] coalesced rows (slot-lo).
//   k_inv: stage f6 coalesced->LDS; V=H*(f6*H); acc->LDS tile; drain fused
//          with coalesced x residual add -> f32 out, in-place per slot.
// d_out slot map (16 KiB per img): lo 8 KiB = f6, hi 8 KiB = F via Faddr().
// d_ws unused (size unknown -> not trusted).

typedef __attribute__((ext_vector_type(4))) float f32x4_t;
typedef __attribute__((ext_vector_type(8))) __bf16 bf16x8_t;
typedef __attribute__((ext_vector_type(8))) unsigned short u16x8_t;
typedef __attribute__((ext_vector_type(4))) unsigned short u16x4_t;

__device__ __forceinline__ float bf2f(unsigned short u) {
  union { unsigned int i; float f; } x; x.i = ((unsigned int)u) << 16; return x.f;
}
__device__ __forceinline__ unsigned short f2bf(float f) {   // RNE
  union { float f; unsigned int i; } x; x.f = f;
  unsigned int i = x.i;
  return (unsigned short)((i + 0x7FFFu + ((i >> 16) & 1u)) >> 16);
}
__device__ __forceinline__ unsigned short f2bf_t(float f) { // truncate (staging)
  union { float f; unsigned int i; } x; x.f = f;
  return (unsigned short)(x.i >> 16);
}
// linear u16 index into F -> physical u16 offset in d_out (slot upper halves)
__device__ __forceinline__ size_t Faddr(size_t f) {
  return ((f >> 12) << 13) + 4096 + (f & 4095);
}

// ---------------- k_fwd: 2D WHT via MFMA, write F tiled ----------------
// block = 512 thr = 8 waves, wave -> image c = cg*8+wave; grid (32 cg, 32 b)
__global__ __launch_bounds__(512) void k_fwd(const float* __restrict__ x,
                                             unsigned short* __restrict__ obuf) {
  __shared__ unsigned short smem[36864];       // 72 KiB: 8x T1t(4608) / Fbuf overlay
  int tid = threadIdx.x;
  int lane = tid & 63, wave = tid >> 6;
  int quad = lane >> 4, l15 = lane & 15;
  int cg = blockIdx.x, b = blockIdx.y;
  size_t img = (size_t)b * 256 + cg * 8 + wave;
  unsigned short* T1t = smem + wave * 4608;    // per-wave [64][72] u16 tile

  // stage X coalesced: flat float4 -> bf16 tile [h][w] (stride 72)
  const float* xim = x + img * 4096;
#pragma unroll
  for (int l = 0; l < 16; l++) {
    int e = (l * 64 + lane) * 4;
    f32x4_t sv = *(const f32x4_t*)(xim + e);
    u16x4_t u;
#pragma unroll
    for (int j = 0; j < 4; j++) u[j] = f2bf_t(sv[j]);
    int row = e >> 6, col = e & 63;
    *(u16x4_t*)&T1t[row * 72 + col] = u;
  }

  // H fragments: hf[kc][t][j] = sign(parity((kc*32+quad*8+j) & (t*16+l15)))
  bf16x8_t hf[2][4];
#pragma unroll
  for (int kc = 0; kc < 2; kc++)
#pragma unroll
    for (int t = 0; t < 4; t++) {
      bf16x8_t h;
#pragma unroll
      for (int j = 0; j < 8; j++) {
        int k = kc * 32 + quad * 8 + j, n = t * 16 + l15;
        h[j] = (__builtin_popcount(k & n) & 1) ? (__bf16)-1.0f : (__bf16)1.0f;
      }
      hf[kc][t] = h;
    }

  // X A-fragments from LDS (b128, same-wave ordering after staging writes)
  bf16x8_t xa[4][2];
#pragma unroll
  for (int mt = 0; mt < 4; mt++)
#pragma unroll
    for (int kc = 0; kc < 2; kc++)
      xa[mt][kc] = *(const bf16x8_t*)&T1t[(mt * 16 + l15) * 72 + kc * 32 + quad * 8];

  // GEMM1: T1 = X*H, strip-mined by nt; store transposed [kw][h] into T1t
  // (overwrites staging tile; all xa reads retired before first write)
#pragma unroll
  for (int nt = 0; nt < 4; nt++) {
    f32x4_t a1c[4];
#pragma unroll
    for (int mt = 0; mt < 4; mt++) a1c[mt] = (f32x4_t){0.f, 0.f, 0.f, 0.f};
#pragma unroll
    for (int kc = 0; kc < 2; kc++)
#pragma unroll
      for (int mt = 0; mt < 4; mt++)
        a1c[mt] = __builtin_amdgcn_mfma_f32_16x16x32_bf16(xa[mt][kc], hf[kc][nt], a1c[mt], 0, 0, 0);
#pragma unroll
    for (int mt = 0; mt < 4; mt++) {
      u16x4_t t4;
#pragma unroll
      for (int r = 0; r < 4; r++) t4[r] = f2bf_t(a1c[mt][r]);
      *(u16x4_t*)&T1t[(nt * 16 + l15) * 72 + mt * 16 + quad * 4] = t4;
    }
  }

  // GEMM2: f2 = H*T1
  f32x4_t acc[4][4];
#pragma unroll
  for (int mt = 0; mt < 4; mt++)
#pragma unroll
    for (int nt = 0; nt < 4; nt++) acc[mt][nt] = (f32x4_t){0.f, 0.f, 0.f, 0.f};
#pragma unroll
  for (int kc = 0; kc < 2; kc++)
#pragma unroll
    for (int nt = 0; nt < 4; nt++) {
      bf16x8_t bfr = *(bf16x8_t*)&T1t[(nt * 16 + l15) * 72 + kc * 32 + quad * 8];
#pragma unroll
      for (int mt = 0; mt < 4; mt++)
        acc[mt][nt] = __builtin_amdgcn_mfma_f32_16x16x32_bf16(hf[kc][mt], bfr, acc[mt][nt], 0, 0, 0);
    }

  __syncthreads();                             // all T1t reads done before overlay
  // fill Fbuf[pos][c8]: this wave supplies c-lane = wave
#pragma unroll
  for (int mt = 0; mt < 4; mt++)
#pragma unroll
    for (int nt = 0; nt < 4; nt++)
#pragma unroll
      for (int r = 0; r < 4; r++) {
        int pos = (mt * 16 + quad * 4 + r) * 64 + nt * 16 + l15;  // kh*64+kw
        smem[pos * 8 + wave] = f2bf(acc[mt][nt][r]);
      }
  __syncthreads();
  // drain: coalesced u16x8 stores to F via Faddr
  size_t fbase = ((size_t)b * 32 + cg) * 4096;
#pragma unroll
  for (int i = 0; i < 8; i++) {
    int pos = i * 512 + tid;
    u16x8_t vch = *(u16x8_t*)&smem[pos * 8];
    *(u16x8_t*)(obuf + Faddr((fbase + pos) * 8)) = vch;
  }
}

// ---------------- k_gemm: Wcat @ F + soft-threshold (unchanged R4) ----------------
__global__ __launch_bounds__(256) void k_gemm(const float* __restrict__ Wf,
                                              const float* __restrict__ vv,
                                              const float* __restrict__ TT,
                                              unsigned short* __restrict__ obuf) {
  __shared__ unsigned short smem2[16384];      // A(8192) + B(8192); epi overlay
  unsigned short* Alds = smem2;
  unsigned short* Blds = smem2 + 8192;
  int tid = threadIdx.x;
  int lane = tid & 63, wave = tid >> 6;
  int quad = lane >> 4, l15 = lane & 15;
  int wm = wave & 1, wn = wave >> 1;
  int n0 = blockIdx.x * 128;                   // pos tile
  int m0 = blockIdx.y * 128;                   // Wcat row tile (m=2o+p)
  int b  = blockIdx.z;

  f32x4_t acc[4][4];
#pragma unroll
  for (int mt = 0; mt < 4; mt++)
#pragma unroll
    for (int nt = 0; nt < 4; nt++) acc[mt][nt] = (f32x4_t){0.f, 0.f, 0.f, 0.f};

  for (int ks = 0; ks < 4; ++ks) {
    int k0 = ks * 64;
    u16x8_t va[4], vb[4];
#pragma unroll
    for (int i = 0; i < 4; i++) {
      int idx = i * 256 + tid;
      {                                        // A: W f32 -> bf16, chunk-swizzled fetch
        int r = idx >> 3, cch = idx & 7;
        int gch = cch ^ (r & 7);
        int m = m0 + r;
        const float* wp = Wf + ((m & 1) << 16) + ((m >> 1) << 8) + k0 + gch * 8;
        f32x4_t w0 = *(const f32x4_t*)wp;
        f32x4_t w1 = *(const f32x4_t*)(wp + 4);
        u16x8_t u;
#pragma unroll
        for (int j = 0; j < 4; j++) { u[j] = f2bf_t(w0[j]); u[4 + j] = f2bf_t(w1[j]); }
        va[i] = u;
      }
      {                                        // B: coalesced fetch, swizzled LDS slot
        int r = idx & 127, cch = idx >> 7;
        size_t f = (((size_t)b * 32 + ks * 8 + cch) * 4096 + n0 + r) * 8;
        vb[i] = *(const u16x8_t*)(obuf + Faddr(f));
      }
    }
#pragma unroll
    for (int i = 0; i < 4; i++) {
      int idx = i * 256 + tid;
      *(u16x8_t*)&Alds[idx * 8] = va[i];       // A: slot cch holds global gch
      int r = idx & 127, cch = idx >> 7;
      int s = cch ^ (r & 7);
      *(u16x8_t*)&Blds[r * 64 + s * 8] = vb[i];// B: slot s holds global cch
    }
    __syncthreads();

#pragma unroll
    for (int kk = 0; kk < 2; ++kk) {
      bf16x8_t af[4], bfr[4];
#pragma unroll
      for (int mt = 0; mt < 4; mt++) {
        int row = wm * 64 + mt * 16 + l15;
        int ch = (kk * 4 + quad) ^ (row & 7);
        af[mt] = *(const bf16x8_t*)&Alds[row * 64 + ch * 8];
      }
#pragma unroll
      for (int nt = 0; nt < 4; nt++) {
        int row = wn * 64 + nt * 16 + l15;
        int ch = (kk * 4 + quad) ^ (row & 7);
        bfr[nt] = *(const bf16x8_t*)&Blds[row * 64 + ch * 8];
      }
#pragma unroll
      for (int mt = 0; mt < 4; mt++)
#pragma unroll
        for (int nt = 0; nt < 4; nt++)
          acc[mt][nt] = __builtin_amdgcn_mfma_f32_16x16x32_bf16(af[mt], bfr[nt], acc[mt][nt], 0, 0, 0);
    }
    __syncthreads();
  }

  // epilogue: v-scale + soft-threshold both pods (reg parity = pod)
  // -> LDS tile [64 o][136 pos-stride] -> coalesced f6 row stores (slot-lo)
#pragma unroll
  for (int nt = 0; nt < 4; nt++) {
    int posl = wn * 64 + nt * 16 + l15;
    int pos = n0 + posl;
    float v0 = vv[pos], v1 = vv[4096 + pos];
    float t0 = TT[pos], t1 = TT[4096 + pos];
#pragma unroll
    for (int mt = 0; mt < 4; mt++)
#pragma unroll
      for (int rp = 0; rp < 2; rp++) {
        int ol = wm * 32 + mt * 8 + quad * 2 + rp;
        float z0 = acc[mt][nt][rp * 2 + 0] * v0;
        float z1 = acc[mt][nt][rp * 2 + 1] * v1;
        float s0 = copysignf(fmaxf(fabsf(z0) - t0, 0.f), z0);
        float s1 = copysignf(fmaxf(fabsf(z1) - t1, 0.f), z1);
        smem2[ol * 136 + posl] = f2bf(s0 + s1);
      }
  }
  __syncthreads();
  int o0 = m0 >> 1;
#pragma unroll
  for (int i = 0; i < 4; i++) {
    int ci = i * 256 + tid;                    // 1024 chunks = 64 rows x 16
    int row = ci >> 4, cc = ci & 15;
    u16x8_t vch = *(u16x8_t*)&smem2[row * 136 + cc * 8];
    size_t img = (size_t)b * 256 + o0 + row;
    *(u16x8_t*)(obuf + img * 8192 + n0 + cc * 8) = vch;
  }
}

// ---------------- k_inv: inverse 2D WHT via MFMA + /4096 + x ----------------
// block = 256 thr = 4 waves, wave -> image; grid 2048
__global__ __launch_bounds__(256) void k_inv(const float* __restrict__ x,
                                             unsigned short* __restrict__ obuf) {
  __shared__ unsigned short smem[18432];       // 4x per-wave [64][72] u16 tile
  int tid = threadIdx.x;
  int lane = tid & 63, wave = tid >> 6;
  int quad = lane >> 4, l15 = lane & 15;
  size_t img = (size_t)blockIdx.x * 4 + wave;
  unsigned short* T1t = smem + wave * 4608;

  // stage f6 coalesced (slot-lo u16x8) -> LDS tile [h][w] stride 72
#pragma unroll
  for (int l = 0; l < 8; l++) {
    int e = (l * 64 + lane) * 8;
    u16x8_t sv = *(const u16x8_t*)(obuf + img * 8192 + e);
    int row = e >> 6, col = e & 63;
    *(u16x8_t*)&T1t[row * 72 + col] = sv;
  }

  bf16x8_t hf[2][4];
#pragma unroll
  for (int kc = 0; kc < 2; kc++)
#pragma unroll
    for (int t = 0; t < 4; t++) {
      bf16x8_t h;
#pragma unroll
      for (int j = 0; j < 8; j++) {
        int k = kc * 32 + quad * 8 + j, n = t * 16 + l15;
        h[j] = (__builtin_popcount(k & n) & 1) ? (__bf16)-1.0f : (__bf16)1.0f;
      }
      hf[kc][t] = h;
    }

  // A-frags from LDS
  bf16x8_t fa[4][2];
#pragma unroll
  for (int mt = 0; mt < 4; mt++)
#pragma unroll
    for (int kc = 0; kc < 2; kc++)
      fa[mt][kc] = *(const bf16x8_t*)&T1t[(mt * 16 + l15) * 72 + kc * 32 + quad * 8];

  // GEMM1: U = f6*H, strip-mined; store transposed into T1t (reuse)
#pragma unroll
  for (int nt = 0; nt < 4; nt++) {
    f32x4_t a1c[4];
#pragma unroll
    for (int mt = 0; mt < 4; mt++) a1c[mt] = (f32x4_t){0.f, 0.f, 0.f, 0.f};
#pragma unroll
    for (int kc = 0; kc < 2; kc++)
#pragma unroll
      for (int mt = 0; mt < 4; mt++)
        a1c[mt] = __builtin_amdgcn_mfma_f32_16x16x32_bf16(fa[mt][kc], hf[kc][nt], a1c[mt], 0, 0, 0);
#pragma unroll
    for (int mt = 0; mt < 4; mt++) {
      u16x4_t t4;
#pragma unroll
      for (int r = 0; r < 4; r++) t4[r] = f2bf_t(a1c[mt][r]);
      *(u16x4_t*)&T1t[(nt * 16 + l15) * 72 + mt * 16 + quad * 4] = t4;
    }
  }

  // GEMM2: V = H*U
  f32x4_t acc[4][4];
#pragma unroll
  for (int mt = 0; mt < 4; mt++)
#pragma unroll
    for (int nt = 0; nt < 4; nt++) acc[mt][nt] = (f32x4_t){0.f, 0.f, 0.f, 0.f};
#pragma unroll
  for (int kc = 0; kc < 2; kc++)
#pragma unroll
    for (int nt = 0; nt < 4; nt++) {
      bf16x8_t bfr = *(bf16x8_t*)&T1t[(nt * 16 + l15) * 72 + kc * 32 + quad * 8];
#pragma unroll
      for (int mt = 0; mt < 4; mt++)
        acc[mt][nt] = __builtin_amdgcn_mfma_f32_16x16x32_bf16(hf[kc][mt], bfr, acc[mt][nt], 0, 0, 0);
    }

  // acc -> LDS tile [hh][ww] as bf16*(1/4096) (scalar u16 writes, 2-way free)
  const float sc = 1.0f / 4096.0f;
#pragma unroll
  for (int mt = 0; mt < 4; mt++)
#pragma unroll
    for (int nt = 0; nt < 4; nt++)
#pragma unroll
      for (int r = 0; r < 4; r++)
        T1t[(mt * 16 + quad * 4 + r) * 72 + nt * 16 + l15] = f2bf(acc[mt][nt][r] * sc);

  // drain: coalesced — LDS row chunks + x residual -> f32 out (in-place slot)
  float* outf = (float*)obuf;
  const float* xim = x + img * 4096;
#pragma unroll
  for (int l = 0; l < 8; l++) {
    int e = (l * 64 + lane) * 8;
    int row = e >> 6, col = e & 63;
    u16x8_t tv = *(u16x8_t*)&T1t[row * 72 + col];
    f32x4_t x0 = *(const f32x4_t*)(xim + e);
    f32x4_t x1 = *(const f32x4_t*)(xim + e + 4);
    f32x4_t o0, o1;
#pragma unroll
    for (int j = 0; j < 4; j++) { o0[j] = bf2f(tv[j]) + x0[j]; o1[j] = bf2f(tv[4 + j]) + x1[j]; }
    *(f32x4_t*)(outf + img * 4096 + e) = o0;
    *(f32x4_t*)(outf + img * 4096 + e + 4) = o1;
  }
}

extern "C" void kernel_launch(void* const* d_in, const int* in_sizes, int n_in,
                              void* d_out, int out_size, void* d_ws, size_t ws_size,
                              hipStream_t stream) {
  const float* x = (const float*)d_in[0];      // (32,256,64,64) f32
  const float* v = (const float*)d_in[1];      // (2,64,64) f32
  const float* W = (const float*)d_in[2];      // (2,256,256) f32
  const float* T = (const float*)d_in[3];      // (2,64,64) f32
  unsigned short* obuf = (unsigned short*)d_out;
  (void)d_ws; (void)ws_size; (void)in_sizes; (void)n_in; (void)out_size;

  k_fwd<<<dim3(32, 32), 512, 0, stream>>>(x, obuf);
  k_gemm<<<dim3(32, 4, 32), 256, 0, stream>>>(W, v, T, obuf);
  k_inv<<<2048, 256, 0, stream>>>(x, obuf);
}